// Round 6
// baseline (807.669 us; speedup 1.0000x reference)
//
#include <hip/hip_runtime.h>
#include <hip/hip_bf16.h>

#define MT 32
#define EPSV 1e-5f

typedef __attribute__((ext_vector_type(8))) short short8;
typedef __attribute__((ext_vector_type(4))) float floatx4;
typedef __attribute__((ext_vector_type(2))) float floatx2;

__device__ __forceinline__ unsigned short f2bf(float f) {
    unsigned u = __builtin_bit_cast(unsigned, f);
    u += 0x7fff + ((u >> 16) & 1);
    return (unsigned short)(u >> 16);
}
__device__ __forceinline__ float bf2f(short s) {
    unsigned u = ((unsigned)(unsigned short)s) << 16;
    return __builtin_bit_cast(float, u);
}

// ===== lane-ordered weight layout (R4, proven +16%) =====
// Every B-panel a wave consumes in one MFMA step is a contiguous 1 KB chunk:
// chunk[lane][j]; lane = quad*16+l16 holds B[k = ks*32+quad*8+j][n].
// ws layout (shorts):
//   w1L  [64  chunks]  at 0       : c1 = (w*8 +nt)*2 +ks, n = w*128+nt*16+l16
//   w2L  [512 chunks]  at 32768   : c2 = (w*16+ks)*8 +nt, n = w*128+nt*16+l16
//   wh1L [256 chunks]  at 294912  : c3 = (w*16+ks)*4 +nt, col = w*64+nt*16+l16,
//                                   kk = col>>6, d = col&63, element Wh1[kk][k][d]
__global__ void convert_weights(const float* __restrict__ W1, const float* __restrict__ W2,
                                const float* __restrict__ Wh1, short* __restrict__ ws) {
    int idx = blockIdx.x * 256 + threadIdx.x;
    if (idx < 32768) {
        int j = idx & 7, lane = (idx >> 3) & 63, c = idx >> 9;
        int ks = c & 1, nt = (c >> 1) & 7, w = c >> 4;
        int k = ks * 32 + (lane >> 4) * 8 + j;
        int n = w * 128 + nt * 16 + (lane & 15);
        ws[idx] = (short)f2bf(W1[k * 512 + n]);
    } else if (idx < 32768 + 262144) {
        int jdx = idx - 32768;
        int j = jdx & 7, lane = (jdx >> 3) & 63, c = jdx >> 9;
        int nt = c & 7, ks = (c >> 3) & 15, w = c >> 7;
        int k = ks * 32 + (lane >> 4) * 8 + j;
        int n = w * 128 + nt * 16 + (lane & 15);
        ws[idx] = (short)f2bf(W2[k * 512 + n]);
    } else if (idx < 32768 + 262144 + 131072) {
        int jdx = idx - (32768 + 262144);
        int j = jdx & 7, lane = (jdx >> 3) & 63, c = jdx >> 9;
        int nt = c & 3, ks = (c >> 2) & 15, w = c >> 6;
        int k = ks * 32 + (lane >> 4) * 8 + j;
        int col = w * 64 + nt * 16 + (lane & 15);
        int kk = col >> 6, d = col & 63;
        ws[idx] = (short)f2bf(Wh1[(kk * 512 + k) * 64 + d]);
    }
}

// swizzled LDS address for a [32][512] bf16 tile (b128-read conflict-free)
__device__ __forceinline__ int sw(int row, int col) {
    return row * 512 + (((col >> 3) ^ (row & 7)) << 3) + (col & 7);
}

// Register model (verified R1-R5): waves/SIMD = floor(512 / (VGPR+AGPR)).
// R5: VGPR 108 + AGPR 64 = 172 -> 2 waves/SIMD (3x172=516 > 512, misses 3 by 4 regs).
// (256,3) caps at 170; compiler shaves 2 VGPRs (demand 172 vs cap 170 — trivial,
// unlike R2/R3 where cap was far below demand -> spill). 3 waves/SIMD, 3 blocks/CU,
// LDS 3x34KB = 103KB <= 160KB. Tripwire: WRITE_SIZE must stay ~4 MB (else spilled).
__global__ __launch_bounds__(256, 3) void fused_kernel(
    const float* __restrict__ z, const int* __restrict__ x, const int* __restrict__ y,
    const float* __restrict__ b1, const float* __restrict__ g1, const float* __restrict__ be1,
    const float* __restrict__ b2, const float* __restrict__ g2, const float* __restrict__ be2,
    const float* __restrict__ bh1, const float* __restrict__ Wh2, const float* __restrict__ bh2,
    const short* __restrict__ ws, float* __restrict__ out)
{
    __shared__ short tile[MT * 512];      // 32 KB, reused: h1 -> h2 -> t
    __shared__ float pstats[MT][8];       // [row][wave*2 + {sum,sq}]
    __shared__ floatx2 rstats[MT];        // {mean, rstd}

    int tid  = threadIdx.x;
    int wave = tid >> 6;
    int lane = tid & 63;
    int quad = lane >> 4;
    int l16  = lane & 15;
    int blk0 = blockIdx.x * MT;
    int nslab = wave * 128;

    // per-wave lane-ordered weight bases (chunk + lane*8 shorts)
    const short* bbase1 = ws + wave * (16 * 512) + lane * 8;                     // w1L
    const short* bbase2 = ws + 32768 + wave * (16 * 8 * 512) + lane * 8;         // w2L
    const short* bbase3 = ws + 32768 + 262144 + wave * (16 * 4 * 512) + lane * 8;// wh1L

    floatx4 acc[2][8];   // 64 AGPRs — shared by stages 1, 2 AND 3 (union)

    // ================= stage 1: h1 = LN(z @ W1 + b1) -> leaky =================
#pragma unroll
    for (int mt = 0; mt < 2; mt++)
#pragma unroll
        for (int nt = 0; nt < 8; nt++) acc[mt][nt] = (floatx4){0.f, 0.f, 0.f, 0.f};

#pragma unroll
    for (int ks = 0; ks < 2; ks++) {
        short8 afr[2];
#pragma unroll
        for (int mt = 0; mt < 2; mt++) {
            int row = blk0 + mt * 16 + l16;
            const float* zp = z + row * 64 + ks * 32 + quad * 8;
            floatx4 f0 = *(const floatx4*)zp;
            floatx4 f1 = *(const floatx4*)(zp + 4);
            short8 a;
            a[0] = (short)f2bf(f0[0]); a[1] = (short)f2bf(f0[1]);
            a[2] = (short)f2bf(f0[2]); a[3] = (short)f2bf(f0[3]);
            a[4] = (short)f2bf(f1[0]); a[5] = (short)f2bf(f1[1]);
            a[6] = (short)f2bf(f1[2]); a[7] = (short)f2bf(f1[3]);
            afr[mt] = a;
        }
#pragma unroll
        for (int nt = 0; nt < 8; nt++) {
            short8 b = *(const short8*)(bbase1 + (nt * 2 + ks) * 512);
            acc[0][nt] = __builtin_amdgcn_mfma_f32_16x16x32_bf16(afr[0], b, acc[0][nt], 0, 0, 0);
            acc[1][nt] = __builtin_amdgcn_mfma_f32_16x16x32_bf16(afr[1], b, acc[1][nt], 0, 0, 0);
        }
    }

    // bias + in-register LN stats
    {
#pragma unroll
        for (int nt = 0; nt < 8; nt++) {
            float bv = b1[nslab + nt * 16 + l16];
#pragma unroll
            for (int mt = 0; mt < 2; mt++)
#pragma unroll
                for (int r2 = 0; r2 < 4; r2++) acc[mt][nt][r2] += bv;
        }
        float sum[2][4] = {}, sq[2][4] = {};
#pragma unroll
        for (int mt = 0; mt < 2; mt++)
#pragma unroll
            for (int nt = 0; nt < 8; nt++)
#pragma unroll
                for (int r2 = 0; r2 < 4; r2++) {
                    float v = acc[mt][nt][r2];
                    sum[mt][r2] += v; sq[mt][r2] += v * v;
                }
#pragma unroll
        for (int m = 1; m < 16; m <<= 1)
#pragma unroll
            for (int mt = 0; mt < 2; mt++)
#pragma unroll
                for (int r2 = 0; r2 < 4; r2++) {
                    sum[mt][r2] += __shfl_xor(sum[mt][r2], m, 64);
                    sq[mt][r2]  += __shfl_xor(sq[mt][r2],  m, 64);
                }
        if (l16 == 0) {
#pragma unroll
            for (int mt = 0; mt < 2; mt++)
#pragma unroll
                for (int r2 = 0; r2 < 4; r2++) {
                    int row = mt * 16 + quad * 4 + r2;
                    *(floatx2*)&pstats[row][wave * 2] = (floatx2){sum[mt][r2], sq[mt][r2]};
                }
        }
    }
    __syncthreads();
    if (tid < MT) {
        float s = pstats[tid][0] + pstats[tid][2] + pstats[tid][4] + pstats[tid][6];
        float q = pstats[tid][1] + pstats[tid][3] + pstats[tid][5] + pstats[tid][7];
        float mean = s * (1.f / 512.f);
        float var  = q * (1.f / 512.f) - mean * mean;
        rstats[tid] = (floatx2){mean, rsqrtf(var + EPSV)};
    }
    __syncthreads();
    {
        floatx2 st[2][4];
#pragma unroll
        for (int mt = 0; mt < 2; mt++)
#pragma unroll
            for (int r2 = 0; r2 < 4; r2++) st[mt][r2] = rstats[mt * 16 + quad * 4 + r2];
#pragma unroll
        for (int nt = 0; nt < 8; nt++) {
            int col = nslab + nt * 16 + l16;
            float gv = g1[col], bev = be1[col];
#pragma unroll
            for (int mt = 0; mt < 2; mt++)
#pragma unroll
                for (int r2 = 0; r2 < 4; r2++) {
                    int row = mt * 16 + quad * 4 + r2;
                    float f = (acc[mt][nt][r2] - st[mt][r2][0]) * st[mt][r2][1] * gv + bev;
                    f = (f >= 0.f) ? f : 0.2f * f;
                    tile[sw(row, col)] = (short)f2bf(f);
                }
        }
    }
    __syncthreads();

    // ================= stage 2: h2 = LN(h1 @ W2 + b2) -> leaky =================
#pragma unroll
    for (int mt = 0; mt < 2; mt++)
#pragma unroll
        for (int nt = 0; nt < 8; nt++) acc[mt][nt] = (floatx4){0.f, 0.f, 0.f, 0.f};

    for (int ks = 0; ks < 16; ks++) {
        short8 afr[2];
#pragma unroll
        for (int mt = 0; mt < 2; mt++) {
            int row = mt * 16 + l16;
            int cb = ks * 4 + quad;
            afr[mt] = *(short8*)&tile[row * 512 + ((cb ^ (row & 7)) << 3)];
        }
#pragma unroll
        for (int nt = 0; nt < 8; nt++) {
            short8 b = *(const short8*)(bbase2 + (ks * 8 + nt) * 512);
            acc[0][nt] = __builtin_amdgcn_mfma_f32_16x16x32_bf16(afr[0], b, acc[0][nt], 0, 0, 0);
            acc[1][nt] = __builtin_amdgcn_mfma_f32_16x16x32_bf16(afr[1], b, acc[1][nt], 0, 0, 0);
        }
    }
    {
#pragma unroll
        for (int nt = 0; nt < 8; nt++) {
            float bv = b2[nslab + nt * 16 + l16];
#pragma unroll
            for (int mt = 0; mt < 2; mt++)
#pragma unroll
                for (int r2 = 0; r2 < 4; r2++) acc[mt][nt][r2] += bv;
        }
        float sum[2][4] = {}, sq[2][4] = {};
#pragma unroll
        for (int mt = 0; mt < 2; mt++)
#pragma unroll
            for (int nt = 0; nt < 8; nt++)
#pragma unroll
                for (int r2 = 0; r2 < 4; r2++) {
                    float v = acc[mt][nt][r2];
                    sum[mt][r2] += v; sq[mt][r2] += v * v;
                }
#pragma unroll
        for (int m = 1; m < 16; m <<= 1)
#pragma unroll
            for (int mt = 0; mt < 2; mt++)
#pragma unroll
                for (int r2 = 0; r2 < 4; r2++) {
                    sum[mt][r2] += __shfl_xor(sum[mt][r2], m, 64);
                    sq[mt][r2]  += __shfl_xor(sq[mt][r2],  m, 64);
                }
        if (l16 == 0) {
#pragma unroll
            for (int mt = 0; mt < 2; mt++)
#pragma unroll
                for (int r2 = 0; r2 < 4; r2++) {
                    int row = mt * 16 + quad * 4 + r2;
                    *(floatx2*)&pstats[row][wave * 2] = (floatx2){sum[mt][r2], sq[mt][r2]};
                }
        }
    }
    __syncthreads();
    if (tid < MT) {
        float s = pstats[tid][0] + pstats[tid][2] + pstats[tid][4] + pstats[tid][6];
        float q = pstats[tid][1] + pstats[tid][3] + pstats[tid][5] + pstats[tid][7];
        float mean = s * (1.f / 512.f);
        float var  = q * (1.f / 512.f) - mean * mean;
        rstats[tid] = (floatx2){mean, rsqrtf(var + EPSV)};
    }
    __syncthreads();
    {
        floatx2 st[2][4];
#pragma unroll
        for (int mt = 0; mt < 2; mt++)
#pragma unroll
            for (int r2 = 0; r2 < 4; r2++) st[mt][r2] = rstats[mt * 16 + quad * 4 + r2];
#pragma unroll
        for (int nt = 0; nt < 8; nt++) {
            int col = nslab + nt * 16 + l16;
            float gv = g2[col], bev = be2[col];
#pragma unroll
            for (int mt = 0; mt < 2; mt++)
#pragma unroll
                for (int r2 = 0; r2 < 4; r2++) {
                    int row = mt * 16 + quad * 4 + r2;
                    float f = (acc[mt][nt][r2] - st[mt][r2][0]) * st[mt][r2][1] * gv + bev;
                    f = (f >= 0.f) ? f : 0.2f * f;
                    tile[sw(row, col)] = (short)f2bf(f);
                }
        }
    }
    __syncthreads();

    // ===== stage 3: t[k] = relu(h2 @ Wh1[k] + bh1[k]), all 4 heads =====
    // acc[mt][0..3] REUSED (acc values dead after stage-2 LN write) -> no extra AGPRs
#pragma unroll
    for (int mt = 0; mt < 2; mt++)
#pragma unroll
        for (int nt = 0; nt < 4; nt++) acc[mt][nt] = (floatx4){0.f, 0.f, 0.f, 0.f};

    for (int ks = 0; ks < 16; ks++) {
        short8 afr[2];
#pragma unroll
        for (int mt = 0; mt < 2; mt++) {
            int row = mt * 16 + l16;
            int cb = ks * 4 + quad;
            afr[mt] = *(short8*)&tile[row * 512 + ((cb ^ (row & 7)) << 3)];
        }
#pragma unroll
        for (int nt = 0; nt < 4; nt++) {
            short8 b = *(const short8*)(bbase3 + (ks * 4 + nt) * 512);
            acc[0][nt] = __builtin_amdgcn_mfma_f32_16x16x32_bf16(afr[0], b, acc[0][nt], 0, 0, 0);
            acc[1][nt] = __builtin_amdgcn_mfma_f32_16x16x32_bf16(afr[1], b, acc[1][nt], 0, 0, 0);
        }
    }
    __syncthreads();   // all stage-3 tile reads done before t overwrites it
#pragma unroll
    for (int mt = 0; mt < 2; mt++)
#pragma unroll
        for (int nt = 0; nt < 4; nt++) {
            int col = wave * 64 + nt * 16 + l16;   // col = kk*64 + d
            float bias = bh1[col];
#pragma unroll
            for (int r2 = 0; r2 < 4; r2++) {
                int row = mt * 16 + quad * 4 + r2;
                float v = acc[mt][nt][r2] + bias;
                v = (v > 0.f) ? v : 0.f;
                tile[row * 264 + col] = (short)f2bf(v);
            }
        }
    __syncthreads();

    // ================= stage 4: per-row head select, logits, softmax =================
    {
        int r = tid >> 3, is = tid & 7;
        int grow = blk0 + r;
        int kk = 2 * x[grow] + y[grow];
        short8 t8 = *(short8*)&tile[r * 264 + kk * 64 + is * 8];
        const float* wp = Wh2 + kk * 256 + is * 32;
        float lg0 = 0.f, lg1 = 0.f, lg2 = 0.f, lg3 = 0.f;
#pragma unroll
        for (int dd = 0; dd < 8; dd++) {
            float td = bf2f(t8[dd]);
            floatx4 wv = *(const floatx4*)(wp + dd * 4);
            lg0 += td * wv[0]; lg1 += td * wv[1]; lg2 += td * wv[2]; lg3 += td * wv[3];
        }
#pragma unroll
        for (int off = 1; off < 8; off <<= 1) {
            lg0 += __shfl_xor(lg0, off, 64);
            lg1 += __shfl_xor(lg1, off, 64);
            lg2 += __shfl_xor(lg2, off, 64);
            lg3 += __shfl_xor(lg3, off, 64);
        }
        if (is == 0) {
            lg0 += bh2[kk * 4 + 0]; lg1 += bh2[kk * 4 + 1];
            lg2 += bh2[kk * 4 + 2]; lg3 += bh2[kk * 4 + 3];
            float m = fmaxf(fmaxf(lg0, lg1), fmaxf(lg2, lg3));
            float e0 = __expf(lg0 - m), e1 = __expf(lg1 - m);
            float e2 = __expf(lg2 - m), e3 = __expf(lg3 - m);
            float inv = 1.f / (e0 + e1 + e2 + e3);
            floatx4 o = {e0 * inv, e1 * inv, e2 * inv, e3 * inv};
            *(floatx4*)(out + grow * 4) = o;
        }
    }
}

extern "C" void kernel_launch(void* const* d_in, const int* in_sizes, int n_in,
                              void* d_out, int out_size, void* d_ws, size_t ws_size,
                              hipStream_t stream) {
    const float* z   = (const float*)d_in[0];
    const int*   x   = (const int*)d_in[1];
    const int*   y   = (const int*)d_in[2];
    const float* W1  = (const float*)d_in[3];
    const float* b1  = (const float*)d_in[4];
    const float* g1  = (const float*)d_in[5];
    const float* be1 = (const float*)d_in[6];
    const float* W2  = (const float*)d_in[7];
    const float* b2  = (const float*)d_in[8];
    const float* g2  = (const float*)d_in[9];
    const float* be2 = (const float*)d_in[10];
    const float* Wh1 = (const float*)d_in[11];
    const float* bh1 = (const float*)d_in[12];
    const float* Wh2 = (const float*)d_in[13];
    const float* bh2 = (const float*)d_in[14];
    short* ws = (short*)d_ws;
    float* out = (float*)d_out;

    hipLaunchKernelGGL(convert_weights, dim3(1664), dim3(256), 0, stream, W1, W2, Wh1, ws);
    hipLaunchKernelGGL(fused_kernel, dim3(262144 / MT), dim3(256), 0, stream,
                       z, x, y, b1, g1, be1, b2, g2, be2, bh1, Wh2, bh2,
                       (const short*)ws, out);
}

// Round 7
// 519.984 us; speedup vs baseline: 1.5533x; 1.5533x over previous
//
#include <hip/hip_runtime.h>
#include <hip/hip_bf16.h>

#define MT 48
#define NROWS 262144
#define EPSV 1e-5f

typedef __attribute__((ext_vector_type(8))) short short8;
typedef __attribute__((ext_vector_type(4))) float floatx4;
typedef __attribute__((ext_vector_type(2))) float floatx2;

__device__ __forceinline__ unsigned short f2bf(float f) {
    unsigned u = __builtin_bit_cast(unsigned, f);
    u += 0x7fff + ((u >> 16) & 1);
    return (unsigned short)(u >> 16);
}
__device__ __forceinline__ float bf2f(short s) {
    unsigned u = ((unsigned)(unsigned short)s) << 16;
    return __builtin_bit_cast(float, u);
}

// ===== lane-ordered weight layout (R4, proven) — UNCHANGED from R5 =====
// chunk[lane][j]; lane = quad*16+l16 holds B[k = ks*32+quad*8+j][n].
//   w1L  [64  chunks]  at 0       : c1 = (w*8 +nt)*2 +ks, n = w*128+nt*16+l16
//   w2L  [512 chunks]  at 32768   : c2 = (w*16+ks)*8 +nt, n = w*128+nt*16+l16
//   wh1L [256 chunks]  at 294912  : c3 = (w*16+ks)*4 +nt, col = w*64+nt*16+l16,
//                                   kk = col>>6, d = col&63, element Wh1[kk][k][d]
__global__ void convert_weights(const float* __restrict__ W1, const float* __restrict__ W2,
                                const float* __restrict__ Wh1, short* __restrict__ ws) {
    int idx = blockIdx.x * 256 + threadIdx.x;
    if (idx < 32768) {
        int j = idx & 7, lane = (idx >> 3) & 63, c = idx >> 9;
        int ks = c & 1, nt = (c >> 1) & 7, w = c >> 4;
        int k = ks * 32 + (lane >> 4) * 8 + j;
        int n = w * 128 + nt * 16 + (lane & 15);
        ws[idx] = (short)f2bf(W1[k * 512 + n]);
    } else if (idx < 32768 + 262144) {
        int jdx = idx - 32768;
        int j = jdx & 7, lane = (jdx >> 3) & 63, c = jdx >> 9;
        int nt = c & 7, ks = (c >> 3) & 15, w = c >> 7;
        int k = ks * 32 + (lane >> 4) * 8 + j;
        int n = w * 128 + nt * 16 + (lane & 15);
        ws[idx] = (short)f2bf(W2[k * 512 + n]);
    } else if (idx < 32768 + 262144 + 131072) {
        int jdx = idx - (32768 + 262144);
        int j = jdx & 7, lane = (jdx >> 3) & 63, c = jdx >> 9;
        int nt = c & 3, ks = (c >> 2) & 15, w = c >> 6;
        int k = ks * 32 + (lane >> 4) * 8 + j;
        int col = w * 64 + nt * 16 + (lane & 15);
        int kk = col >> 6, d = col & 63;
        ws[idx] = (short)f2bf(Wh1[(kk * 512 + k) * 64 + d]);
    }
}

// swizzled LDS address for a [MT][512] bf16 tile (b128-read conflict-free)
__device__ __forceinline__ int sw(int row, int col) {
    return row * 512 + (((col >> 3) ^ (row & 7)) << 3) + (col & 7);
}

// Register model (verified R1-R6): waves/SIMD = floor(512 / (VGPR+AGPR)).
// LESSON (R2/R3/R6): a launch_bounds cap below natural demand => wholesale
// spill (compiler cannot shave "just 2 regs"). So cap must exceed demand:
// MT=48: acc 3x8 = 96 AGPR + ~115 VGPR = ~211 < 256 cap -> no spill,
// 2 waves/SIMD, 2 blocks/CU (LDS 50KB x2 = 100 <= 160) keeps barrier overlap.
// Weight L2 traffic per row /1.5 vs MT=32 (was ~195us of the 500us wall).
__global__ __launch_bounds__(256, 2) void fused_kernel(
    const float* __restrict__ z, const int* __restrict__ x, const int* __restrict__ y,
    const float* __restrict__ b1, const float* __restrict__ g1, const float* __restrict__ be1,
    const float* __restrict__ b2, const float* __restrict__ g2, const float* __restrict__ be2,
    const float* __restrict__ bh1, const float* __restrict__ Wh2, const float* __restrict__ bh2,
    const short* __restrict__ ws, float* __restrict__ out)
{
    __shared__ short tile[MT * 512];      // 48 KB, reused: h1 -> h2 -> t
    __shared__ float pstats[MT][8];       // [row][wave*2 + {sum,sq}]
    __shared__ floatx2 rstats[MT];        // {mean, rstd}

    int tid  = threadIdx.x;
    int wave = tid >> 6;
    int lane = tid & 63;
    int quad = lane >> 4;
    int l16  = lane & 15;
    int blk0 = blockIdx.x * MT;
    int nslab = wave * 128;

    // per-wave lane-ordered weight bases (chunk + lane*8 shorts)
    const short* bbase1 = ws + wave * (16 * 512) + lane * 8;                     // w1L
    const short* bbase2 = ws + 32768 + wave * (16 * 8 * 512) + lane * 8;         // w2L
    const short* bbase3 = ws + 32768 + 262144 + wave * (16 * 4 * 512) + lane * 8;// wh1L

    floatx4 acc[3][8];   // 96 AGPRs — shared by stages 1, 2 AND 3 (union)

    // ================= stage 1: h1 = LN(z @ W1 + b1) -> leaky =================
#pragma unroll
    for (int mt = 0; mt < 3; mt++)
#pragma unroll
        for (int nt = 0; nt < 8; nt++) acc[mt][nt] = (floatx4){0.f, 0.f, 0.f, 0.f};

#pragma unroll
    for (int ks = 0; ks < 2; ks++) {
        short8 afr[3];
#pragma unroll
        for (int mt = 0; mt < 3; mt++) {
            int row = blk0 + mt * 16 + l16;
            row = (row < NROWS) ? row : (NROWS - 1);      // clamp (last partial block)
            const float* zp = z + row * 64 + ks * 32 + quad * 8;
            floatx4 f0 = *(const floatx4*)zp;
            floatx4 f1 = *(const floatx4*)(zp + 4);
            short8 a;
            a[0] = (short)f2bf(f0[0]); a[1] = (short)f2bf(f0[1]);
            a[2] = (short)f2bf(f0[2]); a[3] = (short)f2bf(f0[3]);
            a[4] = (short)f2bf(f1[0]); a[5] = (short)f2bf(f1[1]);
            a[6] = (short)f2bf(f1[2]); a[7] = (short)f2bf(f1[3]);
            afr[mt] = a;
        }
#pragma unroll
        for (int nt = 0; nt < 8; nt++) {
            short8 b = *(const short8*)(bbase1 + (nt * 2 + ks) * 512);
#pragma unroll
            for (int mt = 0; mt < 3; mt++)
                acc[mt][nt] = __builtin_amdgcn_mfma_f32_16x16x32_bf16(afr[mt], b, acc[mt][nt], 0, 0, 0);
        }
    }

    // bias + in-register LN stats
    {
#pragma unroll
        for (int nt = 0; nt < 8; nt++) {
            float bv = b1[nslab + nt * 16 + l16];
#pragma unroll
            for (int mt = 0; mt < 3; mt++)
#pragma unroll
                for (int r2 = 0; r2 < 4; r2++) acc[mt][nt][r2] += bv;
        }
        float sum[3][4] = {}, sq[3][4] = {};
#pragma unroll
        for (int mt = 0; mt < 3; mt++)
#pragma unroll
            for (int nt = 0; nt < 8; nt++)
#pragma unroll
                for (int r2 = 0; r2 < 4; r2++) {
                    float v = acc[mt][nt][r2];
                    sum[mt][r2] += v; sq[mt][r2] += v * v;
                }
#pragma unroll
        for (int m = 1; m < 16; m <<= 1)
#pragma unroll
            for (int mt = 0; mt < 3; mt++)
#pragma unroll
                for (int r2 = 0; r2 < 4; r2++) {
                    sum[mt][r2] += __shfl_xor(sum[mt][r2], m, 64);
                    sq[mt][r2]  += __shfl_xor(sq[mt][r2],  m, 64);
                }
        if (l16 == 0) {
#pragma unroll
            for (int mt = 0; mt < 3; mt++)
#pragma unroll
                for (int r2 = 0; r2 < 4; r2++) {
                    int row = mt * 16 + quad * 4 + r2;
                    *(floatx2*)&pstats[row][wave * 2] = (floatx2){sum[mt][r2], sq[mt][r2]};
                }
        }
    }
    __syncthreads();
    if (tid < MT) {
        float s = pstats[tid][0] + pstats[tid][2] + pstats[tid][4] + pstats[tid][6];
        float q = pstats[tid][1] + pstats[tid][3] + pstats[tid][5] + pstats[tid][7];
        float mean = s * (1.f / 512.f);
        float var  = q * (1.f / 512.f) - mean * mean;
        rstats[tid] = (floatx2){mean, rsqrtf(var + EPSV)};
    }
    __syncthreads();
    {
        floatx2 st[3][4];
#pragma unroll
        for (int mt = 0; mt < 3; mt++)
#pragma unroll
            for (int r2 = 0; r2 < 4; r2++) st[mt][r2] = rstats[mt * 16 + quad * 4 + r2];
#pragma unroll
        for (int nt = 0; nt < 8; nt++) {
            int col = nslab + nt * 16 + l16;
            float gv = g1[col], bev = be1[col];
#pragma unroll
            for (int mt = 0; mt < 3; mt++)
#pragma unroll
                for (int r2 = 0; r2 < 4; r2++) {
                    int row = mt * 16 + quad * 4 + r2;
                    float f = (acc[mt][nt][r2] - st[mt][r2][0]) * st[mt][r2][1] * gv + bev;
                    f = (f >= 0.f) ? f : 0.2f * f;
                    tile[sw(row, col)] = (short)f2bf(f);
                }
        }
    }
    __syncthreads();

    // ================= stage 2: h2 = LN(h1 @ W2 + b2) -> leaky =================
#pragma unroll
    for (int mt = 0; mt < 3; mt++)
#pragma unroll
        for (int nt = 0; nt < 8; nt++) acc[mt][nt] = (floatx4){0.f, 0.f, 0.f, 0.f};

    for (int ks = 0; ks < 16; ks++) {
        short8 afr[3];
#pragma unroll
        for (int mt = 0; mt < 3; mt++) {
            int row = mt * 16 + l16;
            int cb = ks * 4 + quad;
            afr[mt] = *(short8*)&tile[row * 512 + ((cb ^ (row & 7)) << 3)];
        }
#pragma unroll
        for (int nt = 0; nt < 8; nt++) {
            short8 b = *(const short8*)(bbase2 + (ks * 8 + nt) * 512);
#pragma unroll
            for (int mt = 0; mt < 3; mt++)
                acc[mt][nt] = __builtin_amdgcn_mfma_f32_16x16x32_bf16(afr[mt], b, acc[mt][nt], 0, 0, 0);
        }
    }
    {
#pragma unroll
        for (int nt = 0; nt < 8; nt++) {
            float bv = b2[nslab + nt * 16 + l16];
#pragma unroll
            for (int mt = 0; mt < 3; mt++)
#pragma unroll
                for (int r2 = 0; r2 < 4; r2++) acc[mt][nt][r2] += bv;
        }
        float sum[3][4] = {}, sq[3][4] = {};
#pragma unroll
        for (int mt = 0; mt < 3; mt++)
#pragma unroll
            for (int nt = 0; nt < 8; nt++)
#pragma unroll
                for (int r2 = 0; r2 < 4; r2++) {
                    float v = acc[mt][nt][r2];
                    sum[mt][r2] += v; sq[mt][r2] += v * v;
                }
#pragma unroll
        for (int m = 1; m < 16; m <<= 1)
#pragma unroll
            for (int mt = 0; mt < 3; mt++)
#pragma unroll
                for (int r2 = 0; r2 < 4; r2++) {
                    sum[mt][r2] += __shfl_xor(sum[mt][r2], m, 64);
                    sq[mt][r2]  += __shfl_xor(sq[mt][r2],  m, 64);
                }
        if (l16 == 0) {
#pragma unroll
            for (int mt = 0; mt < 3; mt++)
#pragma unroll
                for (int r2 = 0; r2 < 4; r2++) {
                    int row = mt * 16 + quad * 4 + r2;
                    *(floatx2*)&pstats[row][wave * 2] = (floatx2){sum[mt][r2], sq[mt][r2]};
                }
        }
    }
    __syncthreads();
    if (tid < MT) {
        float s = pstats[tid][0] + pstats[tid][2] + pstats[tid][4] + pstats[tid][6];
        float q = pstats[tid][1] + pstats[tid][3] + pstats[tid][5] + pstats[tid][7];
        float mean = s * (1.f / 512.f);
        float var  = q * (1.f / 512.f) - mean * mean;
        rstats[tid] = (floatx2){mean, rsqrtf(var + EPSV)};
    }
    __syncthreads();
    {
        floatx2 st[3][4];
#pragma unroll
        for (int mt = 0; mt < 3; mt++)
#pragma unroll
            for (int r2 = 0; r2 < 4; r2++) st[mt][r2] = rstats[mt * 16 + quad * 4 + r2];
#pragma unroll
        for (int nt = 0; nt < 8; nt++) {
            int col = nslab + nt * 16 + l16;
            float gv = g2[col], bev = be2[col];
#pragma unroll
            for (int mt = 0; mt < 3; mt++)
#pragma unroll
                for (int r2 = 0; r2 < 4; r2++) {
                    int row = mt * 16 + quad * 4 + r2;
                    float f = (acc[mt][nt][r2] - st[mt][r2][0]) * st[mt][r2][1] * gv + bev;
                    f = (f >= 0.f) ? f : 0.2f * f;
                    tile[sw(row, col)] = (short)f2bf(f);
                }
        }
    }
    __syncthreads();

    // ===== stage 3: t[k] = relu(h2 @ Wh1[k] + bh1[k]), all 4 heads =====
    // acc[mt][0..3] REUSED (dead after stage-2 LN write) -> no extra AGPRs
#pragma unroll
    for (int mt = 0; mt < 3; mt++)
#pragma unroll
        for (int nt = 0; nt < 4; nt++) acc[mt][nt] = (floatx4){0.f, 0.f, 0.f, 0.f};

    for (int ks = 0; ks < 16; ks++) {
        short8 afr[3];
#pragma unroll
        for (int mt = 0; mt < 3; mt++) {
            int row = mt * 16 + l16;
            int cb = ks * 4 + quad;
            afr[mt] = *(short8*)&tile[row * 512 + ((cb ^ (row & 7)) << 3)];
        }
#pragma unroll
        for (int nt = 0; nt < 4; nt++) {
            short8 b = *(const short8*)(bbase3 + (ks * 4 + nt) * 512);
#pragma unroll
            for (int mt = 0; mt < 3; mt++)
                acc[mt][nt] = __builtin_amdgcn_mfma_f32_16x16x32_bf16(afr[mt], b, acc[mt][nt], 0, 0, 0);
        }
    }
    __syncthreads();   // all stage-3 tile reads done before t overwrites it
#pragma unroll
    for (int mt = 0; mt < 3; mt++)
#pragma unroll
        for (int nt = 0; nt < 4; nt++) {
            int col = wave * 64 + nt * 16 + l16;   // col = kk*64 + d
            float bias = bh1[col];
#pragma unroll
            for (int r2 = 0; r2 < 4; r2++) {
                int row = mt * 16 + quad * 4 + r2;
                float v = acc[mt][nt][r2] + bias;
                v = (v > 0.f) ? v : 0.f;
                tile[row * 264 + col] = (short)f2bf(v);
            }
        }
    __syncthreads();

    // ===== stage 4: per-row head select, logits, softmax (4 threads/row) =====
    {
        int r = tid >> 2, is = tid & 3;          // r in 0..63, rows 0..47 valid
        if (r < MT) {
            int grow = blk0 + r;
            int gsafe = (grow < NROWS) ? grow : (NROWS - 1);
            int kk = 2 * x[gsafe] + y[gsafe];
            const short* tp = &tile[r * 264 + kk * 64 + is * 16];
            short8 ta = *(short8*)tp;
            short8 tb = *(short8*)(tp + 8);
            const float* wp = Wh2 + kk * 256 + is * 64;
            float lg0 = 0.f, lg1 = 0.f, lg2 = 0.f, lg3 = 0.f;
#pragma unroll
            for (int dd = 0; dd < 8; dd++) {
                float t0 = bf2f(ta[dd]);
                float t1 = bf2f(tb[dd]);
                floatx4 w0 = *(const floatx4*)(wp + dd * 4);
                floatx4 w1 = *(const floatx4*)(wp + 32 + dd * 4);
                lg0 += t0 * w0[0] + t1 * w1[0];
                lg1 += t0 * w0[1] + t1 * w1[1];
                lg2 += t0 * w0[2] + t1 * w1[2];
                lg3 += t0 * w0[3] + t1 * w1[3];
            }
#pragma unroll
            for (int off = 1; off < 4; off <<= 1) {
                lg0 += __shfl_xor(lg0, off, 64);
                lg1 += __shfl_xor(lg1, off, 64);
                lg2 += __shfl_xor(lg2, off, 64);
                lg3 += __shfl_xor(lg3, off, 64);
            }
            if (is == 0 && grow < NROWS) {
                lg0 += bh2[kk * 4 + 0]; lg1 += bh2[kk * 4 + 1];
                lg2 += bh2[kk * 4 + 2]; lg3 += bh2[kk * 4 + 3];
                float m = fmaxf(fmaxf(lg0, lg1), fmaxf(lg2, lg3));
                float e0 = __expf(lg0 - m), e1 = __expf(lg1 - m);
                float e2 = __expf(lg2 - m), e3 = __expf(lg3 - m);
                float inv = 1.f / (e0 + e1 + e2 + e3);
                floatx4 o = {e0 * inv, e1 * inv, e2 * inv, e3 * inv};
                *(floatx4*)(out + grow * 4) = o;
            }
        }
    }
}

extern "C" void kernel_launch(void* const* d_in, const int* in_sizes, int n_in,
                              void* d_out, int out_size, void* d_ws, size_t ws_size,
                              hipStream_t stream) {
    const float* z   = (const float*)d_in[0];
    const int*   x   = (const int*)d_in[1];
    const int*   y   = (const int*)d_in[2];
    const float* W1  = (const float*)d_in[3];
    const float* b1  = (const float*)d_in[4];
    const float* g1  = (const float*)d_in[5];
    const float* be1 = (const float*)d_in[6];
    const float* W2  = (const float*)d_in[7];
    const float* b2  = (const float*)d_in[8];
    const float* g2  = (const float*)d_in[9];
    const float* be2 = (const float*)d_in[10];
    const float* Wh1 = (const float*)d_in[11];
    const float* bh1 = (const float*)d_in[12];
    const float* Wh2 = (const float*)d_in[13];
    const float* bh2 = (const float*)d_in[14];
    short* ws = (short*)d_ws;
    float* out = (float*)d_out;

    hipLaunchKernelGGL(convert_weights, dim3(1664), dim3(256), 0, stream, W1, W2, Wh1, ws);
    hipLaunchKernelGGL(fused_kernel, dim3((NROWS + MT - 1) / MT), dim3(256), 0, stream,
                       z, x, y, b1, g1, be1, b2, g2, be2, bh1, Wh2, bh2,
                       (const short*)ws, out);
}